// Round 1
// baseline (483.823 us; speedup 1.0000x reference)
//
#include <hip/hip_runtime.h>
#include <hip/hip_bf16.h>

#define B_ 4
#define S_ 2048
#define D_ 1024
#define H_ 16
#define HD_ 64
#define M_ (B_*S_)
#define BH_ (B_*H_)

typedef __bf16 bf16;
typedef __attribute__((ext_vector_type(8))) __bf16 bf16x8;
typedef __attribute__((ext_vector_type(4))) __bf16 bf16x4;
typedef __attribute__((ext_vector_type(4))) float f32x4;

#define MFMA16(a,b,c) __builtin_amdgcn_mfma_f32_16x16x32_bf16((a),(b),(c),0,0,0)

__device__ __forceinline__ void gl2lds16(const void* g, void* l) {
  __builtin_amdgcn_global_load_lds(
      (__attribute__((address_space(1))) void*)(g),
      (__attribute__((address_space(3))) void*)(l), 16, 0, 0);
}

// ---------------- f32 -> bf16 convert ----------------
__global__ __launch_bounds__(256) void k_cvt(const float* __restrict__ in,
                                             bf16* __restrict__ out, int n) {
  int i = (blockIdx.x * 256 + threadIdx.x) * 4;
  if (i >= n) return;
  f32x4 v = *(const f32x4*)(in + i);
  bf16x4 o;
  o[0] = (bf16)v[0]; o[1] = (bf16)v[1]; o[2] = (bf16)v[2]; o[3] = (bf16)v[3];
  *(bf16x4*)(out + i) = o;
}

// ---------------- bf16 GEMM: C[m,n] = sum_k A[m,k]*W[n,k] + bias[n] ----------------
// tile 128x128, BK=64, 4 waves (2x2), swizzled LDS (pre-swizzled global source).
// EPI 0: bf16 out, head layout [b,h,s,hd]
// EPI 1: bf16 out, transposed head layout [b,h,hd,s]  (for V)
// EPI 2: f32 out, Y = C + bias + Xres (row-major [M,D])
template <int EPI>
__global__ __launch_bounds__(256) void k_gemm(const bf16* __restrict__ A,
                                              const bf16* __restrict__ W,
                                              const float* __restrict__ bias,
                                              const float* __restrict__ Xres,
                                              void* __restrict__ outp) {
  __shared__ __align__(16) bf16 As[128 * 64];
  __shared__ __align__(16) bf16 Bs[128 * 64];
  const int t = threadIdx.x;
  const int l = t & 63, w = t >> 6;
  const int g = l >> 4, c = l & 15;
  const int wm = w >> 1, wn = w & 1;
  const int m0 = blockIdx.y * 128, n0 = blockIdx.x * 128;

  f32x4 acc[4][4];
#pragma unroll
  for (int i = 0; i < 4; ++i)
#pragma unroll
    for (int j = 0; j < 4; ++j) acc[i][j] = (f32x4)(0.0f);

  const int srow = w * 8 + (l >> 3);
  const int schk = l & 7;

  for (int kt = 0; kt < D_ / 64; ++kt) {
    const int k0 = kt * 64;
#pragma unroll
    for (int p = 0; p < 4; ++p) {
      const int row = p * 32 + srow;
      const int sc = (schk ^ (row & 7)) * 8;
      gl2lds16(A + (size_t)(m0 + row) * D_ + k0 + sc, &As[p * 2048 + w * 512]);
      gl2lds16(W + (size_t)(n0 + row) * D_ + k0 + sc, &Bs[p * 2048 + w * 512]);
    }
    __syncthreads();
#pragma unroll
    for (int kk = 0; kk < 2; ++kk) {
      bf16x8 af[4], bw[4];
#pragma unroll
      for (int i = 0; i < 4; ++i) {
        const int ra = wm * 64 + i * 16 + c;
        af[i] = *(const bf16x8*)&As[ra * 64 + (((kk * 4 + g) ^ (ra & 7)) * 8)];
        const int rb = wn * 64 + i * 16 + c;
        bw[i] = *(const bf16x8*)&Bs[rb * 64 + (((kk * 4 + g) ^ (rb & 7)) * 8)];
      }
#pragma unroll
      for (int i = 0; i < 4; ++i)
#pragma unroll
        for (int j = 0; j < 4; ++j) acc[i][j] = MFMA16(af[i], bw[j], acc[i][j]);
    }
    __syncthreads();
  }

  float bv[4];
#pragma unroll
  for (int j = 0; j < 4; ++j) bv[j] = bias[n0 + wn * 64 + j * 16 + c];

#pragma unroll
  for (int i = 0; i < 4; ++i) {
#pragma unroll
    for (int j = 0; j < 4; ++j) {
#pragma unroll
      for (int r = 0; r < 4; ++r) {
        const int m = m0 + wm * 64 + i * 16 + g * 4 + r;
        const int n = n0 + wn * 64 + j * 16 + c;
        const float v = acc[i][j][r] + bv[j];
        if (EPI == 2) {
          ((float*)outp)[(size_t)m * D_ + n] = v + Xres[(size_t)m * D_ + n];
        } else {
          const int b = m >> 11, s = m & (S_ - 1);
          const int h = n >> 6, hd = n & 63;
          size_t idx;
          if (EPI == 0) idx = (((size_t)(b * H_ + h)) * S_ + s) * HD_ + hd;
          else          idx = (((size_t)(b * H_ + h)) * HD_ + hd) * S_ + s;
          ((bf16*)outp)[idx] = (bf16)v;
        }
      }
    }
  }
}

// ---------------- flash attention ----------------
// grid (S/128, B*H); 4 waves/block, each wave 32 q-rows. K/V tiles 64x64 in LDS.
// Q: [bh][s][d], K: [bh][s][d], Vt: [bh][d][s]. Out: [b,s,D] bf16.
__global__ __launch_bounds__(256) void k_attn(const bf16* __restrict__ Q,
                                              const bf16* __restrict__ K,
                                              const bf16* __restrict__ Vt,
                                              bf16* __restrict__ O) {
  __shared__ __align__(16) bf16 Ks[64 * 64];
  __shared__ __align__(16) bf16 Vs[64 * 64];
  __shared__ __align__(16) bf16 Pl[4][32 * 72];
  const int t = threadIdx.x;
  const int l = t & 63, w = t >> 6;
  const int g = l >> 4, c = l & 15;
  const int bh = blockIdx.y;
  const int q0 = blockIdx.x * 128 + w * 32;
  const bf16* Qh = Q + (size_t)bh * S_ * HD_;
  const bf16* Kh = K + (size_t)bh * S_ * HD_;
  const bf16* Vh = Vt + (size_t)bh * HD_ * S_;

  bf16x8 qf[2][2];
#pragma unroll
  for (int mf = 0; mf < 2; ++mf)
#pragma unroll
    for (int kk = 0; kk < 2; ++kk)
      qf[mf][kk] = *(const bf16x8*)&Qh[(size_t)(q0 + mf * 16 + c) * HD_ + kk * 32 + g * 8];

  f32x4 acc[2][4];
  float m_r[2][4], l_r[2][4];
#pragma unroll
  for (int mf = 0; mf < 2; ++mf) {
#pragma unroll
    for (int j = 0; j < 4; ++j) acc[mf][j] = (f32x4)(0.0f);
#pragma unroll
    for (int r = 0; r < 4; ++r) { m_r[mf][r] = -__builtin_inff(); l_r[mf][r] = 0.f; }
  }

  const int srow = w * 8 + (l >> 3);
  const int schk = l & 7;
  const float SCL = 0.125f * 1.44269504088896340736f;  // 1/sqrt(64) * log2(e)

  for (int kt = 0; kt < S_ / 64; ++kt) {
#pragma unroll
    for (int p = 0; p < 2; ++p) {
      const int row = p * 32 + srow;
      const int sc = (schk ^ (row & 7)) * 8;
      gl2lds16(Kh + (size_t)(kt * 64 + row) * HD_ + sc, &Ks[p * 2048 + w * 512]);
      gl2lds16(Vh + (size_t)row * S_ + kt * 64 + sc, &Vs[p * 2048 + w * 512]);
    }
    __syncthreads();

    // QK^T -> 32x64 scores per wave
    f32x4 s_[2][4];
#pragma unroll
    for (int mf = 0; mf < 2; ++mf)
#pragma unroll
      for (int j = 0; j < 4; ++j) s_[mf][j] = (f32x4)(0.0f);

#pragma unroll
    for (int kk = 0; kk < 2; ++kk) {
      bf16x8 kf[4];
#pragma unroll
      for (int nf = 0; nf < 4; ++nf) {
        const int rw = nf * 16 + c;
        kf[nf] = *(const bf16x8*)&Ks[rw * 64 + (((kk * 4 + g) ^ (rw & 7)) * 8)];
      }
#pragma unroll
      for (int mf = 0; mf < 2; ++mf)
#pragma unroll
        for (int nf = 0; nf < 4; ++nf)
          s_[mf][nf] = MFMA16(qf[mf][kk], kf[nf], s_[mf][nf]);
    }

    // online softmax (rows live in 16-lane groups; reg r -> row 4g+r)
#pragma unroll
    for (int mf = 0; mf < 2; ++mf) {
      float tm[4];
#pragma unroll
      for (int r = 0; r < 4; ++r)
        tm[r] = fmaxf(fmaxf(s_[mf][0][r], s_[mf][1][r]),
                      fmaxf(s_[mf][2][r], s_[mf][3][r]));
#pragma unroll
      for (int mk = 1; mk <= 8; mk <<= 1)
#pragma unroll
        for (int r = 0; r < 4; ++r) tm[r] = fmaxf(tm[r], __shfl_xor(tm[r], mk));
      float mn[4], cf[4], rs[4];
#pragma unroll
      for (int r = 0; r < 4; ++r) {
        mn[r] = fmaxf(m_r[mf][r], tm[r]);
        cf[r] = exp2f((m_r[mf][r] - mn[r]) * SCL);
        m_r[mf][r] = mn[r];
        rs[r] = 0.f;
      }
#pragma unroll
      for (int nf = 0; nf < 4; ++nf)
#pragma unroll
        for (int r = 0; r < 4; ++r) {
          const float p = exp2f((s_[mf][nf][r] - mn[r]) * SCL);
          rs[r] += p;
          Pl[w][(mf * 16 + 4 * g + r) * 72 + nf * 16 + c] = (bf16)p;
        }
#pragma unroll
      for (int mk = 1; mk <= 8; mk <<= 1)
#pragma unroll
        for (int r = 0; r < 4; ++r) rs[r] += __shfl_xor(rs[r], mk);
#pragma unroll
      for (int r = 0; r < 4; ++r) l_r[mf][r] = l_r[mf][r] * cf[r] + rs[r];
#pragma unroll
      for (int j = 0; j < 4; ++j)
#pragma unroll
        for (int r = 0; r < 4; ++r) acc[mf][j][r] *= cf[r];
    }

    // PV: acc += P(32x64) * V(64x64)
#pragma unroll
    for (int kk = 0; kk < 2; ++kk) {
      bf16x8 vf[4];
#pragma unroll
      for (int nf = 0; nf < 4; ++nf) {
        const int rw = nf * 16 + c;
        vf[nf] = *(const bf16x8*)&Vs[rw * 64 + (((kk * 4 + g) ^ (rw & 7)) * 8)];
      }
      bf16x8 pa[2];
#pragma unroll
      for (int mf = 0; mf < 2; ++mf)
        pa[mf] = *(const bf16x8*)&Pl[w][(mf * 16 + c) * 72 + kk * 32 + g * 8];
#pragma unroll
      for (int mf = 0; mf < 2; ++mf)
#pragma unroll
        for (int nf = 0; nf < 4; ++nf)
          acc[mf][nf] = MFMA16(pa[mf], vf[nf], acc[mf][nf]);
    }
    __syncthreads();
  }

  const int b = bh >> 4, h = bh & 15;
#pragma unroll
  for (int mf = 0; mf < 2; ++mf)
#pragma unroll
    for (int nf = 0; nf < 4; ++nf)
#pragma unroll
      for (int r = 0; r < 4; ++r) {
        const int q = q0 + mf * 16 + g * 4 + r;
        const int dv = nf * 16 + c;
        const float o = acc[mf][nf][r] / l_r[mf][r];
        O[((size_t)(b * S_ + q)) * D_ + h * 64 + dv] = (bf16)o;
      }
}

// ---------------- LayerNorm (one block per row) ----------------
__global__ __launch_bounds__(256) void k_ln(const float* __restrict__ Y,
                                            const float* __restrict__ gamma,
                                            const float* __restrict__ beta,
                                            float* __restrict__ out) {
  __shared__ float red[8];
  const int row = blockIdx.x, t = threadIdx.x;
  const float* y = Y + (size_t)row * D_;
  f32x4 v = *(const f32x4*)(y + t * 4);
  float s = v[0] + v[1] + v[2] + v[3];
  float s2 = v[0]*v[0] + v[1]*v[1] + v[2]*v[2] + v[3]*v[3];
#pragma unroll
  for (int mk = 1; mk <= 32; mk <<= 1) {
    s += __shfl_xor(s, mk);
    s2 += __shfl_xor(s2, mk);
  }
  if ((t & 63) == 0) { red[t >> 6] = s; red[4 + (t >> 6)] = s2; }
  __syncthreads();
  const float ts = red[0] + red[1] + red[2] + red[3];
  const float ts2 = red[4] + red[5] + red[6] + red[7];
  const float mu = ts * (1.0f / D_);
  const float inv = rsqrtf(ts2 * (1.0f / D_) - mu * mu + 1e-12f);
  f32x4 gm = *(const f32x4*)(gamma + t * 4);
  f32x4 bt = *(const f32x4*)(beta + t * 4);
  f32x4 o;
#pragma unroll
  for (int j = 0; j < 4; ++j) o[j] = gm[j] * (v[j] - mu) * inv + bt[j];
  *(f32x4*)(out + (size_t)row * D_ + t * 4) = o;
}

extern "C" void kernel_launch(void* const* d_in, const int* in_sizes, int n_in,
                              void* d_out, int out_size, void* d_ws, size_t ws_size,
                              hipStream_t stream) {
  const float* X     = (const float*)d_in[0];
  const float* Wq    = (const float*)d_in[1];
  const float* bq    = (const float*)d_in[2];
  const float* Wk    = (const float*)d_in[3];
  const float* bk    = (const float*)d_in[4];
  const float* Wv    = (const float*)d_in[5];
  const float* bv    = (const float*)d_in[6];
  const float* Wo    = (const float*)d_in[7];
  const float* bo    = (const float*)d_in[8];
  const float* gamma = (const float*)d_in[9];
  const float* beta  = (const float*)d_in[10];

  char* ws = (char*)d_ws;
  bf16* Xb  = (bf16*)(ws + 0);                 // 16 MB
  bf16* Wqb = (bf16*)(ws + (16u << 20));       // 2 MB
  bf16* Wkb = (bf16*)(ws + (18u << 20));       // 2 MB
  bf16* Wvb = (bf16*)(ws + (20u << 20));       // 2 MB
  bf16* Wob = (bf16*)(ws + (22u << 20));       // 2 MB
  bf16* Qb  = (bf16*)(ws + (24u << 20));       // 16 MB [bh][s][d]
  bf16* Kb  = (bf16*)(ws + (40u << 20));       // 16 MB [bh][s][d]
  bf16* Vt  = (bf16*)(ws + (56u << 20));       // 16 MB [bh][d][s]
  bf16* Ob  = (bf16*)(ws + (72u << 20));       // 16 MB [b,s,D]
  float* Yb = (float*)(ws + (88u << 20));      // 32 MB

  k_cvt<<<M_ * D_ / 1024, 256, 0, stream>>>(X, Xb, M_ * D_);
  k_cvt<<<D_ * D_ / 1024, 256, 0, stream>>>(Wq, Wqb, D_ * D_);
  k_cvt<<<D_ * D_ / 1024, 256, 0, stream>>>(Wk, Wkb, D_ * D_);
  k_cvt<<<D_ * D_ / 1024, 256, 0, stream>>>(Wv, Wvb, D_ * D_);
  k_cvt<<<D_ * D_ / 1024, 256, 0, stream>>>(Wo, Wob, D_ * D_);

  dim3 gg(D_ / 128, M_ / 128);
  k_gemm<0><<<gg, 256, 0, stream>>>(Xb, Wqb, bq, nullptr, Qb);
  k_gemm<0><<<gg, 256, 0, stream>>>(Xb, Wkb, bk, nullptr, Kb);
  k_gemm<1><<<gg, 256, 0, stream>>>(Xb, Wvb, bv, nullptr, Vt);
  k_attn<<<dim3(S_ / 128, BH_), 256, 0, stream>>>(Qb, Kb, Vt, Ob);
  k_gemm<2><<<gg, 256, 0, stream>>>(Ob, Wob, bo, X, Yb);
  k_ln<<<M_, 256, 0, stream>>>(Yb, gamma, beta, (float*)d_out);
}

// Round 2
// 335.165 us; speedup vs baseline: 1.4435x; 1.4435x over previous
//
#include <hip/hip_runtime.h>
#include <hip/hip_bf16.h>

#define B_ 4
#define S_ 2048
#define D_ 1024
#define H_ 16
#define HD_ 64
#define M_ (B_*S_)
#define BH_ (B_*H_)

typedef __bf16 bf16;
typedef __attribute__((ext_vector_type(8))) __bf16 bf16x8;
typedef __attribute__((ext_vector_type(4))) __bf16 bf16x4;
typedef __attribute__((ext_vector_type(4))) float f32x4;

#define MFMA16(a,b,c) __builtin_amdgcn_mfma_f32_16x16x32_bf16((a),(b),(c),0,0,0)

__device__ __forceinline__ void gl2lds16(const void* g, void* l) {
  __builtin_amdgcn_global_load_lds(
      (__attribute__((address_space(1))) void*)(g),
      (__attribute__((address_space(3))) void*)(l), 16, 0, 0);
}

__device__ __forceinline__ float fexp2(float x) {
  float r;
  asm("v_exp_f32 %0, %1" : "=v"(r) : "v"(x));
  return r;
}

// ---------------- f32 -> bf16 convert ----------------
__global__ __launch_bounds__(256) void k_cvt(const float* __restrict__ in,
                                             bf16* __restrict__ out, int n) {
  int i = (blockIdx.x * 256 + threadIdx.x) * 4;
  if (i >= n) return;
  f32x4 v = *(const f32x4*)(in + i);
  bf16x4 o;
  o[0] = (bf16)v[0]; o[1] = (bf16)v[1]; o[2] = (bf16)v[2]; o[3] = (bf16)v[3];
  *(bf16x4*)(out + i) = o;
}

// ---------------- bf16 GEMM: C[m,n] = (sum_k A[m,k]*W[n,k] + bias[n]) * scale ----
// tile 128x128, BK=64, 8 waves (2x4, 64x32 each), double-buffered LDS,
// 2-phase pipeline (stage t+1 before compute t, one barrier per tile).
// EPI 0: bf16 out, head layout [b,h,s,hd]
// EPI 1: bf16 out, transposed head layout [b,h,hd,s]  (for V)
// EPI 2: f32 out, Y = C + bias + Xres (row-major [M,D])
template <int EPI>
__global__ __launch_bounds__(512, 4) void k_gemm(const bf16* __restrict__ A,
                                                 const bf16* __restrict__ W,
                                                 const float* __restrict__ bias,
                                                 const float* __restrict__ Xres,
                                                 void* __restrict__ outp,
                                                 float scale) {
  __shared__ __align__(16) bf16 As[2][128 * 64];
  __shared__ __align__(16) bf16 Bs[2][128 * 64];
  const int t = threadIdx.x;
  const int l = t & 63, w = t >> 6;
  const int g = l >> 4, c = l & 15;
  const int wm = w >> 2, wn = w & 3;
  const int m0 = blockIdx.y * 128, n0 = blockIdx.x * 128;

  f32x4 acc[4][2];
#pragma unroll
  for (int i = 0; i < 4; ++i)
#pragma unroll
    for (int j = 0; j < 2; ++j) acc[i][j] = (f32x4)(0.0f);

  const int srow = t >> 3;   // 0..63
  const int schk = t & 7;

#define STG(buf, k0)                                                          \
  do {                                                                        \
    for (int p = 0; p < 2; ++p) {                                             \
      const int row = p * 64 + srow;                                          \
      const int sc = (schk ^ (row & 7)) * 8;                                  \
      gl2lds16(A + (size_t)(m0 + row) * D_ + (k0) + sc,                       \
               &As[buf][p * 4096 + t * 8]);                                   \
      gl2lds16(W + (size_t)(n0 + row) * D_ + (k0) + sc,                       \
               &Bs[buf][p * 4096 + t * 8]);                                   \
    }                                                                         \
  } while (0)

  STG(0, 0);
  __syncthreads();

  for (int kt = 0; kt < D_ / 64; ++kt) {
    const int cur = kt & 1;
    if (kt + 1 < D_ / 64) STG(cur ^ 1, (kt + 1) * 64);
#pragma unroll
    for (int kk = 0; kk < 2; ++kk) {
      bf16x8 af[4], bw[2];
#pragma unroll
      for (int i = 0; i < 4; ++i) {
        const int ra = wm * 64 + i * 16 + c;
        af[i] = *(const bf16x8*)&As[cur][ra * 64 + (((kk * 4 + g) ^ (ra & 7)) * 8)];
      }
#pragma unroll
      for (int j = 0; j < 2; ++j) {
        const int rb = wn * 32 + j * 16 + c;
        bw[j] = *(const bf16x8*)&Bs[cur][rb * 64 + (((kk * 4 + g) ^ (rb & 7)) * 8)];
      }
#pragma unroll
      for (int i = 0; i < 4; ++i)
#pragma unroll
        for (int j = 0; j < 2; ++j) acc[i][j] = MFMA16(af[i], bw[j], acc[i][j]);
    }
    __syncthreads();
  }
#undef STG

  float bv[2];
#pragma unroll
  for (int j = 0; j < 2; ++j) bv[j] = bias[n0 + wn * 32 + j * 16 + c];

#pragma unroll
  for (int i = 0; i < 4; ++i) {
#pragma unroll
    for (int j = 0; j < 2; ++j) {
#pragma unroll
      for (int r = 0; r < 4; ++r) {
        const int m = m0 + wm * 64 + i * 16 + g * 4 + r;
        const int n = n0 + wn * 32 + j * 16 + c;
        const float v = (acc[i][j][r] + bv[j]) * scale;
        if (EPI == 2) {
          ((float*)outp)[(size_t)m * D_ + n] = v + Xres[(size_t)m * D_ + n];
        } else {
          const int b = m >> 11, s = m & (S_ - 1);
          const int h = n >> 6, hd = n & 63;
          size_t idx;
          if (EPI == 0) idx = (((size_t)(b * H_ + h)) * S_ + s) * HD_ + hd;
          else          idx = (((size_t)(b * H_ + h)) * HD_ + hd) * S_ + s;
          ((bf16*)outp)[idx] = (bf16)v;
        }
      }
    }
  }
}

// ---------------- flash attention (swapped QK^T, 8 waves, dbuf pipeline) ------
// grid (S/256, B*H); 8 waves/block, each wave 32 q-rows. K/V tiles 64x64,
// double-buffered. Q pre-scaled by 1/sqrt(HD)*log2(e) in the Q-GEMM epilogue.
// S^T = mfma(K, Q): col = q = lane&15, row-in-frag nf: k = nf*16 + 4g + r.
// Softmax state per lane scalar (q = c). P staged per-wave in LDS (stride 72),
// read back as A-fragments for PV.
__global__ __launch_bounds__(512, 4) void k_attn(const bf16* __restrict__ Q,
                                                 const bf16* __restrict__ K,
                                                 const bf16* __restrict__ Vt,
                                                 bf16* __restrict__ O) {
  __shared__ __align__(16) bf16 Ks[2][64 * 64];
  __shared__ __align__(16) bf16 Vs[2][64 * 64];
  __shared__ __align__(16) bf16 Pl[8][16 * 72];
  const int t = threadIdx.x;
  const int l = t & 63, w = t >> 6;
  const int g = l >> 4, c = l & 15;
  const int bh = blockIdx.y;
  const int q0 = blockIdx.x * 256 + w * 32;
  const bf16* Qh = Q + (size_t)bh * S_ * HD_;
  const bf16* Kh = K + (size_t)bh * S_ * HD_;
  const bf16* Vh = Vt + (size_t)bh * HD_ * S_;

  bf16x8 qf[2][2];
#pragma unroll
  for (int mf = 0; mf < 2; ++mf)
#pragma unroll
    for (int kk = 0; kk < 2; ++kk)
      qf[mf][kk] = *(const bf16x8*)&Qh[(size_t)(q0 + mf * 16 + c) * HD_ + kk * 32 + g * 8];

  f32x4 acc[2][4];
  float m_c[2], l_c[2];
#pragma unroll
  for (int mf = 0; mf < 2; ++mf) {
#pragma unroll
    for (int nf = 0; nf < 4; ++nf) acc[mf][nf] = (f32x4)(0.0f);
    m_c[mf] = -__builtin_inff();
    l_c[mf] = 0.f;
  }

  const int srow = t >> 3, schk = t & 7;

#define STGA(buf, kt)                                                         \
  do {                                                                        \
    const int sck = (schk ^ (srow & 7)) * 8;                                  \
    gl2lds16(Kh + (size_t)((kt) * 64 + srow) * HD_ + sck, &Ks[buf][t * 8]);   \
    gl2lds16(Vh + (size_t)srow * S_ + (kt) * 64 + sck, &Vs[buf][t * 8]);      \
  } while (0)

  STGA(0, 0);
  __syncthreads();

  for (int kt = 0; kt < S_ / 64; ++kt) {
    const int cur = kt & 1;
    if (kt + 1 < S_ / 64) STGA(cur ^ 1, kt + 1);

    // S^T = K * Q^T
    f32x4 st[2][4];
#pragma unroll
    for (int mf = 0; mf < 2; ++mf)
#pragma unroll
      for (int nf = 0; nf < 4; ++nf) st[mf][nf] = (f32x4)(0.0f);

#pragma unroll
    for (int kk = 0; kk < 2; ++kk) {
      bf16x8 kf[4];
#pragma unroll
      for (int nf = 0; nf < 4; ++nf) {
        const int rw = nf * 16 + c;
        kf[nf] = *(const bf16x8*)&Ks[cur][rw * 64 + (((kk * 4 + g) ^ (rw & 7)) * 8)];
      }
#pragma unroll
      for (int mf = 0; mf < 2; ++mf)
#pragma unroll
        for (int nf = 0; nf < 4; ++nf)
          st[mf][nf] = MFMA16(kf[nf], qf[mf][kk], st[mf][nf]);
    }

#pragma unroll
    for (int mf = 0; mf < 2; ++mf) {
      // row max over this tile's 64 k for q=c
      float tm = st[mf][0][0];
#pragma unroll
      for (int nf = 0; nf < 4; ++nf)
#pragma unroll
        for (int r = 0; r < 4; ++r)
          if (nf || r) tm = fmaxf(tm, st[mf][nf][r]);
      tm = fmaxf(tm, __shfl_xor(tm, 16));
      tm = fmaxf(tm, __shfl_xor(tm, 32));
      const float mn = fmaxf(m_c[mf], tm);
      const float cfq = fexp2(m_c[mf] - mn);
      m_c[mf] = mn;
      float rs = 0.f;
#pragma unroll
      for (int nf = 0; nf < 4; ++nf) {
        bf16x4 pv;
#pragma unroll
        for (int r = 0; r < 4; ++r) {
          const float p = fexp2(st[mf][nf][r] - mn);
          rs += p;
          pv[r] = (bf16)p;
        }
        *(bf16x4*)&Pl[w][c * 72 + nf * 16 + 4 * g] = pv;
      }
      rs += __shfl_xor(rs, 16);
      rs += __shfl_xor(rs, 32);
      l_c[mf] = l_c[mf] * cfq + rs;

      // rescale acc (acc rows live at q = 4g+r; cfq lives at q = c)
      float cfr[4];
#pragma unroll
      for (int r = 0; r < 4; ++r) cfr[r] = __shfl(cfq, 4 * g + r);
#pragma unroll
      for (int nf = 0; nf < 4; ++nf)
#pragma unroll
        for (int r = 0; r < 4; ++r) acc[mf][nf][r] *= cfr[r];

      // PV for this mf: acc += P(16x64) * V(64x64)
#pragma unroll
      for (int kk = 0; kk < 2; ++kk) {
        bf16x8 pa = *(const bf16x8*)&Pl[w][c * 72 + kk * 32 + g * 8];
        bf16x8 vf[4];
#pragma unroll
        for (int nf = 0; nf < 4; ++nf) {
          const int rw = nf * 16 + c;
          vf[nf] = *(const bf16x8*)&Vs[cur][rw * 64 + (((kk * 4 + g) ^ (rw & 7)) * 8)];
        }
#pragma unroll
        for (int nf = 0; nf < 4; ++nf)
          acc[mf][nf] = MFMA16(pa, vf[nf], acc[mf][nf]);
      }
    }
    __syncthreads();
  }
#undef STGA

  const int b = bh >> 4, h = bh & 15;
#pragma unroll
  for (int mf = 0; mf < 2; ++mf) {
    float li[4];
#pragma unroll
    for (int r = 0; r < 4; ++r)
      li[r] = __builtin_amdgcn_rcpf(__shfl(l_c[mf], 4 * g + r));
#pragma unroll
    for (int nf = 0; nf < 4; ++nf)
#pragma unroll
      for (int r = 0; r < 4; ++r) {
        const int q = q0 + mf * 16 + 4 * g + r;
        const int dv = nf * 16 + c;
        O[((size_t)(b * S_ + q)) * D_ + h * 64 + dv] = (bf16)(acc[mf][nf][r] * li[r]);
      }
  }
}

// ---------------- LayerNorm (one block per row) ----------------
__global__ __launch_bounds__(256) void k_ln(const float* __restrict__ Y,
                                            const float* __restrict__ gamma,
                                            const float* __restrict__ beta,
                                            float* __restrict__ out) {
  __shared__ float red[8];
  const int row = blockIdx.x, t = threadIdx.x;
  const float* y = Y + (size_t)row * D_;
  f32x4 v = *(const f32x4*)(y + t * 4);
  float s = v[0] + v[1] + v[2] + v[3];
  float s2 = v[0]*v[0] + v[1]*v[1] + v[2]*v[2] + v[3]*v[3];
#pragma unroll
  for (int mk = 1; mk <= 32; mk <<= 1) {
    s += __shfl_xor(s, mk);
    s2 += __shfl_xor(s2, mk);
  }
  if ((t & 63) == 0) { red[t >> 6] = s; red[4 + (t >> 6)] = s2; }
  __syncthreads();
  const float ts = red[0] + red[1] + red[2] + red[3];
  const float ts2 = red[4] + red[5] + red[6] + red[7];
  const float mu = ts * (1.0f / D_);
  const float inv = rsqrtf(ts2 * (1.0f / D_) - mu * mu + 1e-12f);
  f32x4 gm = *(const f32x4*)(gamma + t * 4);
  f32x4 bt = *(const f32x4*)(beta + t * 4);
  f32x4 o;
#pragma unroll
  for (int j = 0; j < 4; ++j) o[j] = gm[j] * (v[j] - mu) * inv + bt[j];
  *(f32x4*)(out + (size_t)row * D_ + t * 4) = o;
}

extern "C" void kernel_launch(void* const* d_in, const int* in_sizes, int n_in,
                              void* d_out, int out_size, void* d_ws, size_t ws_size,
                              hipStream_t stream) {
  const float* X     = (const float*)d_in[0];
  const float* Wq    = (const float*)d_in[1];
  const float* bq    = (const float*)d_in[2];
  const float* Wk    = (const float*)d_in[3];
  const float* bk    = (const float*)d_in[4];
  const float* Wv    = (const float*)d_in[5];
  const float* bv    = (const float*)d_in[6];
  const float* Wo    = (const float*)d_in[7];
  const float* bo    = (const float*)d_in[8];
  const float* gamma = (const float*)d_in[9];
  const float* beta  = (const float*)d_in[10];

  char* ws = (char*)d_ws;
  bf16* Xb  = (bf16*)(ws + 0);                 // 16 MB
  bf16* Wqb = (bf16*)(ws + (16u << 20));       // 2 MB
  bf16* Wkb = (bf16*)(ws + (18u << 20));       // 2 MB
  bf16* Wvb = (bf16*)(ws + (20u << 20));       // 2 MB
  bf16* Wob = (bf16*)(ws + (22u << 20));       // 2 MB
  bf16* Qb  = (bf16*)(ws + (24u << 20));       // 16 MB [bh][s][d] (pre-scaled)
  bf16* Kb  = (bf16*)(ws + (40u << 20));       // 16 MB [bh][s][d]
  bf16* Vt  = (bf16*)(ws + (56u << 20));       // 16 MB [bh][d][s]
  bf16* Ob  = (bf16*)(ws + (72u << 20));       // 16 MB [b,s,D]
  float* Yb = (float*)(ws + (88u << 20));      // 32 MB

  const float SCL = 0.125f * 1.44269504088896340736f;  // 1/sqrt(64) * log2(e)

  k_cvt<<<M_ * D_ / 1024, 256, 0, stream>>>(X, Xb, M_ * D_);
  k_cvt<<<D_ * D_ / 1024, 256, 0, stream>>>(Wq, Wqb, D_ * D_);
  k_cvt<<<D_ * D_ / 1024, 256, 0, stream>>>(Wk, Wkb, D_ * D_);
  k_cvt<<<D_ * D_ / 1024, 256, 0, stream>>>(Wv, Wvb, D_ * D_);
  k_cvt<<<D_ * D_ / 1024, 256, 0, stream>>>(Wo, Wob, D_ * D_);

  dim3 gg(D_ / 128, M_ / 128);
  k_gemm<0><<<gg, 512, 0, stream>>>(Xb, Wqb, bq, nullptr, Qb, SCL);
  k_gemm<0><<<gg, 512, 0, stream>>>(Xb, Wkb, bk, nullptr, Kb, 1.0f);
  k_gemm<1><<<gg, 512, 0, stream>>>(Xb, Wvb, bv, nullptr, Vt, 1.0f);
  k_attn<<<dim3(S_ / 256, BH_), 512, 0, stream>>>(Qb, Kb, Vt, Ob);
  k_gemm<2><<<gg, 512, 0, stream>>>(Ob, Wob, bo, X, Yb, 1.0f);
  k_ln<<<M_, 256, 0, stream>>>(Yb, gamma, beta, (float*)d_out);
}

// Round 5
// 329.922 us; speedup vs baseline: 1.4665x; 1.0159x over previous
//
#include <hip/hip_runtime.h>
#include <hip/hip_bf16.h>

#define B_ 4
#define S_ 2048
#define D_ 1024
#define H_ 16
#define HD_ 64
#define M_ (B_*S_)
#define BH_ (B_*H_)

typedef __bf16 bf16;
typedef __attribute__((ext_vector_type(8))) __bf16 bf16x8;
typedef __attribute__((ext_vector_type(4))) __bf16 bf16x4;
typedef __attribute__((ext_vector_type(4))) float f32x4;
typedef __attribute__((ext_vector_type(16))) float f32x16;
typedef __attribute__((ext_vector_type(4))) unsigned u32x4;

#define MFMA16(a,b,c) __builtin_amdgcn_mfma_f32_16x16x32_bf16((a),(b),(c),0,0,0)
#define MFMA32(a,b,c) __builtin_amdgcn_mfma_f32_32x32x16_bf16((a),(b),(c),0,0,0)

__device__ __forceinline__ void gl2lds16(const void* g, void* l) {
  __builtin_amdgcn_global_load_lds(
      (__attribute__((address_space(1))) void*)(g),
      (__attribute__((address_space(3))) void*)(l), 16, 0, 0);
}

__device__ __forceinline__ float fexp2(float x) {
  float r;
  asm("v_exp_f32 %0, %1" : "=v"(r) : "v"(x));
  return r;
}

__device__ __forceinline__ unsigned cvtpk(float lo, float hi) {
  unsigned r;
  asm("v_cvt_pk_bf16_f32 %0, %1, %2" : "=v"(r) : "v"(lo), "v"(hi));
  return r;
}

// ---------------- f32 -> bf16 convert ----------------
__global__ __launch_bounds__(256) void k_cvt(const float* __restrict__ in,
                                             bf16* __restrict__ out, int n) {
  int i = (blockIdx.x * 256 + threadIdx.x) * 4;
  if (i >= n) return;
  f32x4 v = *(const f32x4*)(in + i);
  bf16x4 o;
  o[0] = (bf16)v[0]; o[1] = (bf16)v[1]; o[2] = (bf16)v[2]; o[3] = (bf16)v[3];
  *(bf16x4*)(out + i) = o;
}

// ---------------- bf16 GEMM (unchanged from R2) ----------------
template <int EPI>
__global__ __launch_bounds__(512, 4) void k_gemm(const bf16* __restrict__ A,
                                                 const bf16* __restrict__ W,
                                                 const float* __restrict__ bias,
                                                 const float* __restrict__ Xres,
                                                 void* __restrict__ outp,
                                                 float scale) {
  __shared__ __align__(16) bf16 As[2][128 * 64];
  __shared__ __align__(16) bf16 Bs[2][128 * 64];
  const int t = threadIdx.x;
  const int l = t & 63, w = t >> 6;
  const int g = l >> 4, c = l & 15;
  const int wm = w >> 2, wn = w & 3;
  const int m0 = blockIdx.y * 128, n0 = blockIdx.x * 128;

  f32x4 acc[4][2];
#pragma unroll
  for (int i = 0; i < 4; ++i)
#pragma unroll
    for (int j = 0; j < 2; ++j) acc[i][j] = (f32x4)(0.0f);

  const int srow = t >> 3;
  const int schk = t & 7;

#define STG(buf, k0)                                                          \
  do {                                                                        \
    for (int p = 0; p < 2; ++p) {                                             \
      const int row = p * 64 + srow;                                          \
      const int sc = (schk ^ (row & 7)) * 8;                                  \
      gl2lds16(A + (size_t)(m0 + row) * D_ + (k0) + sc,                       \
               &As[buf][p * 4096 + t * 8]);                                   \
      gl2lds16(W + (size_t)(n0 + row) * D_ + (k0) + sc,                       \
               &Bs[buf][p * 4096 + t * 8]);                                   \
    }                                                                         \
  } while (0)

  STG(0, 0);
  __syncthreads();

  for (int kt = 0; kt < D_ / 64; ++kt) {
    const int cur = kt & 1;
    if (kt + 1 < D_ / 64) STG(cur ^ 1, (kt + 1) * 64);
#pragma unroll
    for (int kk = 0; kk < 2; ++kk) {
      bf16x8 af[4], bw[2];
#pragma unroll
      for (int i = 0; i < 4; ++i) {
        const int ra = wm * 64 + i * 16 + c;
        af[i] = *(const bf16x8*)&As[cur][ra * 64 + (((kk * 4 + g) ^ (ra & 7)) * 8)];
      }
#pragma unroll
      for (int j = 0; j < 2; ++j) {
        const int rb = wn * 32 + j * 16 + c;
        bw[j] = *(const bf16x8*)&Bs[cur][rb * 64 + (((kk * 4 + g) ^ (rb & 7)) * 8)];
      }
#pragma unroll
      for (int i = 0; i < 4; ++i)
#pragma unroll
        for (int j = 0; j < 2; ++j) acc[i][j] = MFMA16(af[i], bw[j], acc[i][j]);
    }
    __syncthreads();
  }
#undef STG

  float bv[2];
#pragma unroll
  for (int j = 0; j < 2; ++j) bv[j] = bias[n0 + wn * 32 + j * 16 + c];

#pragma unroll
  for (int i = 0; i < 4; ++i) {
#pragma unroll
    for (int j = 0; j < 2; ++j) {
#pragma unroll
      for (int r = 0; r < 4; ++r) {
        const int m = m0 + wm * 64 + i * 16 + g * 4 + r;
        const int n = n0 + wn * 32 + j * 16 + c;
        const float v = (acc[i][j][r] + bv[j]) * scale;
        if (EPI == 2) {
          ((float*)outp)[(size_t)m * D_ + n] = v + Xres[(size_t)m * D_ + n];
        } else {
          const int b = m >> 11, s = m & (S_ - 1);
          const int h = n >> 6, hd = n & 63;
          size_t idx;
          if (EPI == 0) idx = (((size_t)(b * H_ + h)) * S_ + s) * HD_ + hd;
          else          idx = (((size_t)(b * H_ + h)) * HD_ + hd) * S_ + s;
          ((bf16*)outp)[idx] = (bf16)v;
        }
      }
    }
  }
}

// ---------------- flash attention, 32x32 fully-swapped, in-register P ---------
// grid (S/128, B*H), 256 threads = 4 waves, each wave 32 q rows.
// S^T = mfma32(K_frag, Q_frag): col = q = lane&31, row k = (reg&3)+8(reg>>2)+4hi.
// O^T = mfma32(Vt_frag, P^T_frag): col = q, row d.  Softmax state: 1 scalar/lane.
// P^T B-frags built in-register: cvt_pk pairs + v_permlane32_swap_b32 (T12).
__global__ __launch_bounds__(256, 3) void k_attn(const bf16* __restrict__ Q,
                                                 const bf16* __restrict__ K,
                                                 const bf16* __restrict__ Vt,
                                                 bf16* __restrict__ O) {
  __shared__ __align__(16) bf16 Ks[2][64 * 64];
  __shared__ __align__(16) bf16 Vs[2][64 * 64];
  const int t = threadIdx.x;
  const int l = t & 63, w = t >> 6;
  const int c32 = l & 31, hi = l >> 5;
  const int bh = blockIdx.y;
  const int q0 = blockIdx.x * 128 + w * 32;
  const bf16* Qh = Q + (size_t)bh * S_ * HD_;
  const bf16* Kh = K + (size_t)bh * S_ * HD_;
  const bf16* Vh = Vt + (size_t)bh * HD_ * S_;

  // Q B-fragments, persistent in registers (pre-scaled by 1/sqrt(HD)*log2e)
  bf16x8 qf[4];
#pragma unroll
  for (int kk = 0; kk < 4; ++kk)
    qf[kk] = *(const bf16x8*)&Qh[(size_t)(q0 + c32) * HD_ + kk * 16 + hi * 8];

  f32x16 acc0 = (f32x16)(0.f), acc1 = (f32x16)(0.f);
  float m_c = -__builtin_inff(), l_c = 0.f;

  const int srow = t >> 3, schk = t & 7;
  const int sw = c32 & 7;  // read-side swizzle (rows 0..63: row&7 == c32&7)

#define STGA(buf, kt)                                                         \
  do {                                                                        \
    for (int p = 0; p < 2; ++p) {                                             \
      const int row = p * 32 + srow;                                          \
      const int sc = (schk ^ (row & 7)) * 8;                                  \
      gl2lds16(Kh + (size_t)((kt) * 64 + row) * HD_ + sc,                     \
               &Ks[buf][p * 2048 + t * 8]);                                   \
      gl2lds16(Vh + (size_t)row * S_ + (kt) * 64 + sc,                        \
               &Vs[buf][p * 2048 + t * 8]);                                   \
    }                                                                         \
  } while (0)

  STGA(0, 0);
  __syncthreads();

  for (int kt = 0; kt < S_ / 64; ++kt) {
    const int cur = kt & 1;
    if (kt + 1 < S_ / 64) STGA(cur ^ 1, kt + 1);

    // ---- QK^T (swapped): st = K * Q^T, two 32-k tiles ----
    f32x16 st0 = (f32x16)(0.f), st1 = (f32x16)(0.f);
    __builtin_amdgcn_s_setprio(1);
#pragma unroll
    for (int kk = 0; kk < 4; ++kk) {
      const int slot = ((kk * 2 + hi) ^ sw) * 8;
      bf16x8 kf0 = *(const bf16x8*)&Ks[cur][c32 * 64 + slot];
      bf16x8 kf1 = *(const bf16x8*)&Ks[cur][(32 + c32) * 64 + slot];
      st0 = MFMA32(kf0, qf[kk], st0);
      st1 = MFMA32(kf1, qf[kk], st1);
    }
    __builtin_amdgcn_s_setprio(0);

    // ---- online softmax, one scalar state per lane (q = c32) ----
    float tm;
    {
      f32x16 mx;
#pragma unroll
      for (int r = 0; r < 16; ++r) mx[r] = fmaxf(st0[r], st1[r]);
      float m8[8];
#pragma unroll
      for (int r = 0; r < 8; ++r) m8[r] = fmaxf(mx[r], mx[r + 8]);
      float m4[4];
#pragma unroll
      for (int r = 0; r < 4; ++r) m4[r] = fmaxf(m8[r], m8[r + 4]);
      tm = fmaxf(fmaxf(m4[0], m4[1]), fmaxf(m4[2], m4[3]));
      tm = fmaxf(tm, __shfl_xor(tm, 32));
    }
    if (!__all(tm <= m_c + 8.f)) {   // defer-max (T13): rescale only on growth
      const float mn = fmaxf(m_c, tm);
      const float cf = fexp2(m_c - mn);
      m_c = mn;
      l_c *= cf;
#pragma unroll
      for (int r = 0; r < 16; ++r) { acc0[r] *= cf; acc1[r] *= cf; }
    }
    float rs = 0.f;
#pragma unroll
    for (int r = 0; r < 16; ++r) { st0[r] = fexp2(st0[r] - m_c); rs += st0[r]; }
#pragma unroll
    for (int r = 0; r < 16; ++r) { st1[r] = fexp2(st1[r] - m_c); rs += st1[r]; }
    rs += __shfl_xor(rs, 32);
    l_c += rs;

    // ---- P^T -> bf16 B-fragments in-register (cvt_pk + permlane32_swap) ----
    unsigned ca[8], cb[8];
#pragma unroll
    for (int i = 0; i < 8; ++i) {
      ca[i] = cvtpk(st0[2 * i], st0[2 * i + 1]);
      cb[i] = cvtpk(st1[2 * i], st1[2 * i + 1]);
    }
    asm volatile("v_permlane32_swap_b32 %0, %1" : "+v"(ca[0]), "+v"(ca[2]));
    asm volatile("v_permlane32_swap_b32 %0, %1" : "+v"(ca[1]), "+v"(ca[3]));
    asm volatile("v_permlane32_swap_b32 %0, %1" : "+v"(ca[4]), "+v"(ca[6]));
    asm volatile("v_permlane32_swap_b32 %0, %1" : "+v"(ca[5]), "+v"(ca[7]));
    asm volatile("v_permlane32_swap_b32 %0, %1" : "+v"(cb[0]), "+v"(cb[2]));
    asm volatile("v_permlane32_swap_b32 %0, %1" : "+v"(cb[1]), "+v"(cb[3]));
    asm volatile("v_permlane32_swap_b32 %0, %1" : "+v"(cb[4]), "+v"(cb[6]));
    asm volatile("v_permlane32_swap_b32 %0, %1" : "+v"(cb[5]), "+v"(cb[7]));
    bf16x8 pf[4];
    pf[0] = __builtin_bit_cast(bf16x8, (u32x4){ca[0], ca[1], ca[2], ca[3]});
    pf[1] = __builtin_bit_cast(bf16x8, (u32x4){ca[4], ca[5], ca[6], ca[7]});
    pf[2] = __builtin_bit_cast(bf16x8, (u32x4){cb[0], cb[1], cb[2], cb[3]});
    pf[3] = __builtin_bit_cast(bf16x8, (u32x4){cb[4], cb[5], cb[6], cb[7]});

    // ---- PV (swapped): acc(O^T) += V^T * P^T ----
    __builtin_amdgcn_s_setprio(1);
#pragma unroll
    for (int kb = 0; kb < 4; ++kb) {
      const int slot = ((kb * 2 + hi) ^ sw) * 8;
      bf16x8 vf0 = *(const bf16x8*)&Vs[cur][c32 * 64 + slot];
      bf16x8 vf1 = *(const bf16x8*)&Vs[cur][(32 + c32) * 64 + slot];
      acc0 = MFMA32(vf0, pf[kb], acc0);
      acc1 = MFMA32(vf1, pf[kb], acc1);
    }
    __builtin_amdgcn_s_setprio(0);

    __syncthreads();
  }
#undef STGA

  const float li = 1.f / l_c;
  const int b = bh >> 4, h = bh & 15;
  const int q = q0 + c32;
  bf16* Orow = O + ((size_t)(b * S_ + q)) * D_ + h * 64;
#pragma unroll
  for (int rq = 0; rq < 4; ++rq) {
    bf16x4 o0, o1;
#pragma unroll
    for (int j = 0; j < 4; ++j) {
      o0[j] = (bf16)(acc0[rq * 4 + j] * li);
      o1[j] = (bf16)(acc1[rq * 4 + j] * li);
    }
    *(bf16x4*)&Orow[rq * 8 + hi * 4] = o0;
    *(bf16x4*)&Orow[32 + rq * 8 + hi * 4] = o1;
  }
}

// ---------------- LayerNorm (one block per row) ----------------
__global__ __launch_bounds__(256) void k_ln(const float* __restrict__ Y,
                                            const float* __restrict__ gamma,
                                            const float* __restrict__ beta,
                                            float* __restrict__ out) {
  __shared__ float red[8];
  const int row = blockIdx.x, t = threadIdx.x;
  const float* y = Y + (size_t)row * D_;
  f32x4 v = *(const f32x4*)(y + t * 4);
  float s = v[0] + v[1] + v[2] + v[3];
  float s2 = v[0]*v[0] + v[1]*v[1] + v[2]*v[2] + v[3]*v[3];
#pragma unroll
  for (int mk = 1; mk <= 32; mk <<= 1) {
    s += __shfl_xor(s, mk);
    s2 += __shfl_xor(s2, mk);
  }
  if ((t & 63) == 0) { red[t >> 6] = s; red[4 + (t >> 6)] = s2; }
  __syncthreads();
  const float ts = red[0] + red[1] + red[2] + red[3];
  const float ts2 = red[4] + red[5] + red[6] + red[7];
  const float mu = ts * (1.0f / D_);
  const float inv = rsqrtf(ts2 * (1.0f / D_) - mu * mu + 1e-12f);
  f32x4 gm = *(const f32x4*)(gamma + t * 4);
  f32x4 bt = *(const f32x4*)(beta + t * 4);
  f32x4 o;
#pragma unroll
  for (int j = 0; j < 4; ++j) o[j] = gm[j] * (v[j] - mu) * inv + bt[j];
  *(f32x4*)(out + (size_t)row * D_ + t * 4) = o;
}

extern "C" void kernel_launch(void* const* d_in, const int* in_sizes, int n_in,
                              void* d_out, int out_size, void* d_ws, size_t ws_size,
                              hipStream_t stream) {
  const float* X     = (const float*)d_in[0];
  const float* Wq    = (const float*)d_in[1];
  const float* bq    = (const float*)d_in[2];
  const float* Wk    = (const float*)d_in[3];
  const float* bk    = (const float*)d_in[4];
  const float* Wv    = (const float*)d_in[5];
  const float* bv    = (const float*)d_in[6];
  const float* Wo    = (const float*)d_in[7];
  const float* bo    = (const float*)d_in[8];
  const float* gamma = (const float*)d_in[9];
  const float* beta  = (const float*)d_in[10];

  char* ws = (char*)d_ws;
  bf16* Xb  = (bf16*)(ws + 0);                 // 16 MB
  bf16* Wqb = (bf16*)(ws + (16u << 20));       // 2 MB
  bf16* Wkb = (bf16*)(ws + (18u << 20));       // 2 MB
  bf16* Wvb = (bf16*)(ws + (20u << 20));       // 2 MB
  bf16* Wob = (bf16*)(ws + (22u << 20));       // 2 MB
  bf16* Qb  = (bf16*)(ws + (24u << 20));       // 16 MB [bh][s][d] (pre-scaled)
  bf16* Kb  = (bf16*)(ws + (40u << 20));       // 16 MB [bh][s][d]
  bf16* Vt  = (bf16*)(ws + (56u << 20));       // 16 MB [bh][d][s]
  bf16* Ob  = (bf16*)(ws + (72u << 20));       // 16 MB [b,s,D]
  float* Yb = (float*)(ws + (88u << 20));      // 32 MB

  const float SCL = 0.125f * 1.44269504088896340736f;  // 1/sqrt(64) * log2(e)

  k_cvt<<<M_ * D_ / 1024, 256, 0, stream>>>(X, Xb, M_ * D_);
  k_cvt<<<D_ * D_ / 1024, 256, 0, stream>>>(Wq, Wqb, D_ * D_);
  k_cvt<<<D_ * D_ / 1024, 256, 0, stream>>>(Wk, Wkb, D_ * D_);
  k_cvt<<<D_ * D_ / 1024, 256, 0, stream>>>(Wv, Wvb, D_ * D_);
  k_cvt<<<D_ * D_ / 1024, 256, 0, stream>>>(Wo, Wob, D_ * D_);

  dim3 gg(D_ / 128, M_ / 128);
  k_gemm<0><<<gg, 512, 0, stream>>>(Xb, Wqb, bq, nullptr, Qb, SCL);
  k_gemm<0><<<gg, 512, 0, stream>>>(Xb, Wkb, bk, nullptr, Kb, 1.0f);
  k_gemm<1><<<gg, 512, 0, stream>>>(Xb, Wvb, bv, nullptr, Vt, 1.0f);
  k_attn<<<dim3(S_ / 128, BH_), 256, 0, stream>>>(Qb, Kb, Vt, Ob);
  k_gemm<2><<<gg, 512, 0, stream>>>(Ob, Wob, bo, X, Yb, 1.0f);
  k_ln<<<M_, 256, 0, stream>>>(Yb, gamma, beta, (float*)d_out);
}